// Round 1
// baseline (199.909 us; speedup 1.0000x reference)
//
#include <hip/hip_runtime.h>

// out[t][e] = (W[e][ids[t]] + b[e]) * sqrt(512)
// W: (512, 50257) row-major f32; ids: 32768 int32; out: 32768 x 512 f32.
//
// Round 5: counted-vmcnt double-buffered scatter pipeline (T3/T4 port).
//  - VB 32->64: one DMA instruction = one 256 B contiguous W-row segment.
//  - ECH 64, 8 chunks, 2 LDS buffers: stage(c+1) stays in flight across a raw
//    s_barrier while scatter(c) runs; per-wave "s_waitcnt vmcnt(16)" (never 0
//    in the main loop). Each wave issues exactly 16 global_load_lds per chunk,
//    so the count is exact; bias/toks loads retire under the one __syncthreads
//    before the pipeline starts.
//  - LDS layout: row r at r*65 dwords (64 used + 1 pad). DMA dest = uniform
//    base + lane*4 (contiguous within a row). Scatter column read
//    addr = lane*65 + vl -> bank (lane+vl)%32 = 2-way only (free, m136).
//  - Non-temporal out stores (write-once data; keep L2/L3 for W slop reuse).
//  - init_counts dispatch replaced by hipMemsetAsync.

constexpr int VOCAB = 50257;
constexpr int EMB   = 512;
constexpr int NTOK  = 8 * 4096;
constexpr float SCALE = 22.62741699796952f;  // sqrt(512)

constexpr int VB  = 64;                      // vocab ids per bucket
constexpr int NB  = (VOCAB + VB - 1) / VB;   // 786 buckets/blocks
constexpr int CAP = 96;                      // capacity (mean 41.7, sigma 6.5)
constexpr int ECH = 64;                      // e-rows staged per chunk
constexpr int NCH = EMB / ECH;               // 8 chunks
constexpr int RS  = VB + 1;                  // LDS row stride in dwords (65)

// d_ws int layout: counts[NB] | ocount[1] | olist[NTOK] | buckets[NB*CAP]

__global__ __launch_bounds__(256) void build_buckets(
    const int* __restrict__ ids,
    int* __restrict__ counts,
    int* __restrict__ olist,
    int* __restrict__ buckets)
{
    int t = blockIdx.x * 256 + threadIdx.x;
    int id = ids[t];
    int bkt = id >> 6;
    int slot = atomicAdd(&counts[bkt], 1);
    if (slot < CAP) {
        buckets[bkt * CAP + slot] = (t << 6) | (id & 63);
    } else {
        int o = atomicAdd(&counts[NB], 1);
        olist[o] = t;
    }
}

__global__ __launch_bounds__(256, 4) void scatter_main(
    const float* __restrict__ W,
    const float* __restrict__ bias,
    const int*   __restrict__ counts,
    const int*   __restrict__ buckets,
    float*       __restrict__ out)
{
    __shared__ float buf[2][ECH * RS];   // 2 x 16,640 B
    __shared__ int   toks[CAP];
    __shared__ int   s_cnt;

    const int b    = blockIdx.x;
    const int tid  = threadIdx.x;
    const int lane = tid & 63;
    const int w    = tid >> 6;           // wave id 0..3

    if (tid == 0) s_cnt = counts[b];
    if (tid < CAP) toks[tid] = buckets[b * CAP + tid];

    // Preload all 8 per-chunk bias values; retired by the __syncthreads drain
    // so no compiler-inserted vmcnt lands inside the pipeline loop.
    float bb[NCH];
    #pragma unroll
    for (int c = 0; c < NCH; ++c) bb[c] = bias[c * ECH + lane];

    int v = b * VB + lane;
    const float* wsrc = W + (v < VOCAB ? v : VOCAB - 1);  // clamp edge lanes

    __syncthreads();                     // toks visible; vmcnt fully drained
    const int cnt = min(s_cnt, CAP);
    if (cnt == 0) return;

    // Wave w stages rows [w*16, w*16+16) of chunk c: 16 DMA instrs per wave,
    // each 64 lanes x 4 B = one contiguous 256 B W-row segment.
    auto stage = [&](int c, int sel) {
        #pragma unroll
        for (int p = 0; p < 16; ++p) {
            const int rr = w * 16 + p;
            const float* gp = wsrc + (size_t)(c * ECH + rr) * VOCAB;
            float* lp = &buf[sel][rr * RS];
            __builtin_amdgcn_global_load_lds(
                (const __attribute__((address_space(1))) void*)gp,
                (__attribute__((address_space(3))) void*)lp, 4, 0, 0);
        }
    };

    stage(0, 0);                         // prologue

    #pragma unroll
    for (int c = 0; c < NCH; ++c) {
        const int sel = c & 1;
        if (c + 1 < NCH) {
            stage(c + 1, sel ^ 1);
            // Wait for chunk c's 16 loads (and prior stores); chunk c+1's 16
            // remain in flight across the barrier.
            asm volatile("s_waitcnt vmcnt(16)" ::: "memory");
        } else {
            asm volatile("s_waitcnt vmcnt(0)" ::: "memory");
        }
        __builtin_amdgcn_s_barrier();

        const float  bc    = bb[c];
        const float* tilec = &buf[sel][lane * RS];
        float*       orow  = out + c * ECH + lane;
        for (int i = w; i < cnt; i += 4) {
            const int pk = toks[i];
            const int t  = pk >> 6;
            const int vl = pk & 63;
            __builtin_nontemporal_store((tilec[vl] + bc) * SCALE,
                                        orow + (size_t)t * EMB);
        }
        if (c + 1 < NCH) __builtin_amdgcn_s_barrier();  // protect buf[sel] reuse
    }
}

// Handles tokens whose bucket overflowed CAP (expected count: 0).
__global__ __launch_bounds__(256) void overflow_fix(
    const int*   __restrict__ counts,
    const int*   __restrict__ olist,
    const int*   __restrict__ ids,
    const float* __restrict__ W,
    const float* __restrict__ bias,
    float*       __restrict__ out)
{
    int n    = counts[NB];
    int wid  = (blockIdx.x * 256 + threadIdx.x) >> 6;
    int lane = threadIdx.x & 63;
    int nw   = (gridDim.x * 256) >> 6;
    for (int ww = wid; ww < n; ww += nw) {
        int t  = olist[ww];
        int id = ids[t];
        #pragma unroll
        for (int m = 0; m < 8; ++m) {
            int e = lane + m * 64;
            out[(size_t)t * EMB + e] = (W[(size_t)e * VOCAB + id] + bias[e]) * SCALE;
        }
    }
}

// Fallback (round-1 kernel) if d_ws is too small.
__global__ __launch_bounds__(256) void embed_gather(
    const int*   __restrict__ ids,
    const float* __restrict__ W,
    const float* __restrict__ b,
    float*       __restrict__ out)
{
    int idx4 = blockIdx.x * blockDim.x + threadIdx.x;
    int t    = idx4 >> 7;
    int e    = (idx4 & 127) << 2;
    int id = ids[t];
    float4 bb = *reinterpret_cast<const float4*>(b + e);
    const float* wcol = W + (size_t)id;
    float4 o;
    o.x = (wcol[(size_t)(e + 0) * VOCAB] + bb.x) * SCALE;
    o.y = (wcol[(size_t)(e + 1) * VOCAB] + bb.y) * SCALE;
    o.z = (wcol[(size_t)(e + 2) * VOCAB] + bb.z) * SCALE;
    o.w = (wcol[(size_t)(e + 3) * VOCAB] + bb.w) * SCALE;
    *reinterpret_cast<float4*>(out + (size_t)idx4 * 4) = o;
}

extern "C" void kernel_launch(void* const* d_in, const int* in_sizes, int n_in,
                              void* d_out, int out_size, void* d_ws, size_t ws_size,
                              hipStream_t stream)
{
    const int*   ids  = (const int*)  d_in[0];
    const float* W    = (const float*)d_in[1];
    const float* bias = (const float*)d_in[2];
    float*       out  = (float*)d_out;

    const size_t ws_ints_needed = (size_t)NB + 1 + NTOK + (size_t)NB * CAP;

    if (ws_size >= ws_ints_needed * sizeof(int)) {
        int* counts  = (int*)d_ws;
        int* olist   = counts + NB + 1;
        int* buckets = olist + NTOK;

        hipMemsetAsync(counts, 0, (NB + 1) * sizeof(int), stream);
        build_buckets<<<NTOK / 256, 256, 0, stream>>>(ids, counts, olist, buckets);
        scatter_main<<<NB, 256, 0, stream>>>(W, bias, counts, buckets, out);
        overflow_fix<<<32, 256, 0, stream>>>(counts, olist, ids, W, bias, out);
    } else {
        constexpr int total4 = NTOK * EMB / 4;
        embed_gather<<<total4 / 256, 256, 0, stream>>>(ids, W, bias, out);
    }
}

// Round 2
// 195.896 us; speedup vs baseline: 1.0205x; 1.0205x over previous
//
#include <hip/hip_runtime.h>

// out[t][e] = (W[e][ids[t]] + b[e]) * sqrt(512)
// W: (512, 50257) row-major f32; ids: 32768 int32; out: 32768 x 512 f32.
//
// Round 6: wave-private scatter, zero-barrier pipeline-by-TLP.
//  - Grid NB*4: block (b,z) = bucket b, E-rows [z*128, z*128+128).
//  - Each wave owns 32 E-rows in a private LDS tile (32 x 65 dwords): stages
//    them with 32 private global_load_lds, waits its OWN vmcnt(0), scatters.
//    No s_barrier after the initial toks load -> waves drift, latency hidden
//    by 12x block oversubscription instead of intra-block pipelining.
//  - LDS read tile[el*65+vl]: bank (el+vl)%32, conflict-free per half-wave.
//  - Scatter handles 2 tokens/iter: lanes 0-31 -> token i, lanes 32-63 ->
//    token i+1; each token gets a contiguous 128 B store segment.
//  - Regular (cached) stores: out+W fit in 256 MB L3; NT gave no benefit and
//    store retirement was being forced by the old vmcnt(16) lockstep.
//  - overflow_fix folded into b==0 blocks (expected n==0).

constexpr int VOCAB = 50257;
constexpr int EMB   = 512;
constexpr int NTOK  = 8 * 4096;
constexpr float SCALE = 22.62741699796952f;  // sqrt(512)

constexpr int VB   = 64;                      // vocab ids per bucket
constexpr int NB   = (VOCAB + VB - 1) / VB;   // 786 buckets
constexpr int CAP  = 96;                      // capacity (mean 41.7, sigma 6.5)
constexpr int ESPL = 4;                       // E-slices per bucket
constexpr int RWV  = 32;                      // E-rows per wave (128/4 waves)
constexpr int RS   = VB + 1;                  // LDS row stride in dwords (65)

// d_ws int layout: counts[NB] | ocount[1] | olist[NTOK] | buckets[NB*CAP]

__global__ __launch_bounds__(256) void build_buckets(
    const int* __restrict__ ids,
    int* __restrict__ counts,
    int* __restrict__ olist,
    int* __restrict__ buckets)
{
    int t = blockIdx.x * 256 + threadIdx.x;
    int id = ids[t];
    int bkt = id >> 6;
    int slot = atomicAdd(&counts[bkt], 1);
    if (slot < CAP) {
        buckets[bkt * CAP + slot] = (t << 6) | (id & 63);
    } else {
        int o = atomicAdd(&counts[NB], 1);
        olist[o] = t;
    }
}

__global__ __launch_bounds__(256) void scatter_main(
    const float* __restrict__ W,
    const float* __restrict__ bias,
    const int*   __restrict__ counts,
    const int*   __restrict__ buckets,
    const int*   __restrict__ olist,
    const int*   __restrict__ ids,
    float*       __restrict__ out)
{
    __shared__ float tile[4][RWV * RS];   // 4 waves x 32x65 dwords = 33,280 B
    __shared__ int   toks[CAP];
    __shared__ int   s_cnt;

    const int bid  = blockIdx.x;
    const int b    = bid >> 2;            // bucket
    const int z    = bid & 3;             // E-slice
    const int tid  = threadIdx.x;
    const int lane = tid & 63;
    const int w    = tid >> 6;            // wave id 0..3

    if (tid == 0) s_cnt = counts[b];
    if (tid < CAP) toks[tid] = buckets[b * CAP + tid];
    __syncthreads();                      // the ONLY block-wide barrier
    const int cnt = min(s_cnt, CAP);

    const int e0 = z * 128 + w * RWV;     // wave's first E-row
    const int el = lane & 31;             // E-row within wave's tile
    const float be = bias[e0 + el];       // per-lane bias (dup across halves)

    const int v = b * VB + lane;
    const float* wsrc = W + (v < VOCAB ? v : VOCAB - 1);  // clamp edge lanes

    if (cnt > 0) {
        // ---- stage: 32 wave-private DMA rows, 256 B each ----
        #pragma unroll
        for (int r = 0; r < RWV; ++r) {
            const float* gp = wsrc + (size_t)(e0 + r) * VOCAB;
            float* lp = &tile[w][r * RS];
            __builtin_amdgcn_global_load_lds(
                (const __attribute__((address_space(1))) void*)gp,
                (__attribute__((address_space(3))) void*)lp, 4, 0, 0);
        }
        // Wait for this wave's own loads only; other waves keep running.
        asm volatile("s_waitcnt vmcnt(0)" ::: "memory");

        // ---- scatter: 2 tokens per iteration ----
        const int half = lane >> 5;
        const float* tw = &tile[w][el * RS];
        for (int i = 0; i < cnt; i += 2) {
            int j  = i + half;
            int jj = j < cnt ? j : cnt - 1;
            int pk = toks[jj];
            int t  = pk >> 6;
            int vl = pk & 63;
            float val = (tw[vl] + be) * SCALE;
            if (j < cnt) out[(size_t)t * EMB + e0 + el] = val;
        }
    }

    // ---- overflow fix (expected n == 0), handled by b==0 blocks ----
    if (b == 0) {
        int n = counts[NB];
        for (int ww = w; ww < n; ww += 4) {
            int t  = olist[ww];
            int id = ids[t];
            #pragma unroll
            for (int m = 0; m < 2; ++m) {
                int e = z * 128 + lane + m * 64;
                out[(size_t)t * EMB + e] = (W[(size_t)e * VOCAB + id] + bias[e]) * SCALE;
            }
        }
    }
}

// Fallback (round-1 kernel) if d_ws is too small.
__global__ __launch_bounds__(256) void embed_gather(
    const int*   __restrict__ ids,
    const float* __restrict__ W,
    const float* __restrict__ b,
    float*       __restrict__ out)
{
    int idx4 = blockIdx.x * blockDim.x + threadIdx.x;
    int t    = idx4 >> 7;
    int e    = (idx4 & 127) << 2;
    int id = ids[t];
    float4 bb = *reinterpret_cast<const float4*>(b + e);
    const float* wcol = W + (size_t)id;
    float4 o;
    o.x = (wcol[(size_t)(e + 0) * VOCAB] + bb.x) * SCALE;
    o.y = (wcol[(size_t)(e + 1) * VOCAB] + bb.y) * SCALE;
    o.z = (wcol[(size_t)(e + 2) * VOCAB] + bb.z) * SCALE;
    o.w = (wcol[(size_t)(e + 3) * VOCAB] + bb.w) * SCALE;
    *reinterpret_cast<float4*>(out + (size_t)idx4 * 4) = o;
}

extern "C" void kernel_launch(void* const* d_in, const int* in_sizes, int n_in,
                              void* d_out, int out_size, void* d_ws, size_t ws_size,
                              hipStream_t stream)
{
    const int*   ids  = (const int*)  d_in[0];
    const float* W    = (const float*)d_in[1];
    const float* bias = (const float*)d_in[2];
    float*       out  = (float*)d_out;

    const size_t ws_ints_needed = (size_t)NB + 1 + NTOK + (size_t)NB * CAP;

    if (ws_size >= ws_ints_needed * sizeof(int)) {
        int* counts  = (int*)d_ws;
        int* olist   = counts + NB + 1;
        int* buckets = olist + NTOK;

        hipMemsetAsync(counts, 0, (NB + 1) * sizeof(int), stream);
        build_buckets<<<NTOK / 256, 256, 0, stream>>>(ids, counts, olist, buckets);
        scatter_main<<<NB * ESPL, 256, 0, stream>>>(W, bias, counts, buckets,
                                                    olist, ids, out);
    } else {
        constexpr int total4 = NTOK * EMB / 4;
        embed_gather<<<total4 / 256, 256, 0, stream>>>(ids, W, bias, out);
    }
}